// Round 1
// baseline (168.725 us; speedup 1.0000x reference)
//
#include <hip/hip_runtime.h>
#include <math.h>

// Problem constants (from reference setup_inputs)
#define BATCH 512
#define LEN   16384
#define WIN   5
#define WOUT  (LEN - WIN + 1)   // 16380

// Kernel 1: per-(window, batch-chunk) partial accumulation.
// thread -> window j; blockIdx.y -> batch chunk; loop over chunk's batches.
// Accumulates sum_b (pvar - tvar)^2 and sum_b msum into workspace partials.
__global__ void bcl_partial_kernel(const float* __restrict__ pred,
                                   const int*   __restrict__ tgt,
                                   const int*   __restrict__ msk,
                                   float* __restrict__ part_d2,
                                   float* __restrict__ part_ms,
                                   int bper) {
    int j = blockIdx.x * blockDim.x + threadIdx.x;
    if (j >= WOUT) return;
    int b0 = blockIdx.y * bper;
    float accd2 = 0.f, accms = 0.f;
    for (int b = b0; b < b0 + bper; ++b) {
        const float2* pr = (const float2*)(pred + ((size_t)b * LEN + j) * 2);
        const int*    tb = tgt + (size_t)b * LEN + j;
        const int*    mb = msk + (size_t)b * LEN + j;
        float msum = 0.f, spm = 0.f, stm = 0.f, sp2m = 0.f;
#pragma unroll
        for (int k = 0; k < WIN; ++k) {
            float  m  = (float)mb[k];
            float  t  = (float)tb[k];
            float2 p2 = pr[k];
            // softmax over 2 classes, class 1: 1/(1+e^{p0-p1})
            float  p  = 1.0f / (1.0f + __expf(p2.x - p2.y));
            msum += m;
            spm  += p * m;
            stm  += t * m;
            sp2m += p * p * m;
        }
        // st2m == stm since t in {0,1}
        float denom = fmaxf(msum, 1.0f);
        float pmean = spm / denom;
        float tmean = stm / denom;
        float pvar  = (sp2m - 2.0f * pmean * spm + pmean * pmean * msum) / denom;
        float tvar  = (stm  - 2.0f * tmean * stm + tmean * tmean * msum) / denom;
        float d = pvar - tvar;
        accd2 += d * d;
        accms += msum;
    }
    part_d2[(size_t)blockIdx.y * WOUT + j] = accd2;
    part_ms[(size_t)blockIdx.y * WOUT + j] = accms;
}

// Kernel 2: per-window reduce over chunks -> mse*valid; block partials (double).
__global__ void bcl_window_reduce(const float* __restrict__ part_d2,
                                  const float* __restrict__ part_ms,
                                  double* __restrict__ blk_out,
                                  int nchunks) {
    int j = blockIdx.x * blockDim.x + threadIdx.x;
    double num = 0.0, cnt = 0.0;
    if (j < WOUT) {
        float d2 = 0.f, ms = 0.f;
        for (int c = 0; c < nchunks; ++c) {
            d2 += part_d2[(size_t)c * WOUT + j];
            ms += part_ms[(size_t)c * WOUT + j];
        }
        if (ms > 0.f) {
            num = (double)d2 * (1.0 / (double)BATCH);
            cnt = 1.0;
        }
    }
    // wave reduce (wave = 64)
    for (int off = 32; off > 0; off >>= 1) {
        num += __shfl_down(num, off, 64);
        cnt += __shfl_down(cnt, off, 64);
    }
    __shared__ double s_num[8], s_cnt[8];
    int lane = threadIdx.x & 63, wave = threadIdx.x >> 6;
    if (lane == 0) { s_num[wave] = num; s_cnt[wave] = cnt; }
    __syncthreads();
    if (threadIdx.x == 0) {
        double n = 0.0, c = 0.0;
        int nw = (int)(blockDim.x >> 6);
        for (int wv = 0; wv < nw; ++wv) { n += s_num[wv]; c += s_cnt[wv]; }
        blk_out[(size_t)blockIdx.x * 2]     = n;
        blk_out[(size_t)blockIdx.x * 2 + 1] = c;
    }
}

// Kernel 3: final reduce of block partials -> scalar loss.
__global__ void bcl_final(const double* __restrict__ blk_out,
                          float* __restrict__ out, int nblk) {
    double num = 0.0, cnt = 0.0;
    for (int i = threadIdx.x; i < nblk; i += 64) {
        num += blk_out[(size_t)i * 2];
        cnt += blk_out[(size_t)i * 2 + 1];
    }
    for (int off = 32; off > 0; off >>= 1) {
        num += __shfl_down(num, off, 64);
        cnt += __shfl_down(cnt, off, 64);
    }
    if (threadIdx.x == 0) out[0] = (float)(num / fmax(cnt, 1.0));
}

extern "C" void kernel_launch(void* const* d_in, const int* in_sizes, int n_in,
                              void* d_out, int out_size, void* d_ws, size_t ws_size,
                              hipStream_t stream) {
    const float* pred = (const float*)d_in[0];
    const int*   tgt  = (const int*)d_in[1];
    const int*   msk  = (const int*)d_in[2];
    float* out = (float*)d_out;

    // Pick largest batch-chunk count that fits in workspace (divides 512).
    int nchunks = 16;
    while (nchunks > 1) {
        size_t need = (size_t)nchunks * WOUT * 2 * sizeof(float) + 64 * 2 * sizeof(double) + 64;
        if (need <= ws_size) break;
        nchunks >>= 1;
    }
    int bper = BATCH / nchunks;

    float* part_d2 = (float*)d_ws;
    float* part_ms = part_d2 + (size_t)nchunks * WOUT;
    // 8-byte align the double block-partials region
    size_t off = ((size_t)nchunks * WOUT * 2 * sizeof(float) + 7) & ~(size_t)7;
    double* blk_out = (double*)((char*)d_ws + off);

    const int TPB = 256;
    const int WBLKS = (WOUT + TPB - 1) / TPB;  // 64

    dim3 g1(WBLKS, nchunks);
    bcl_partial_kernel<<<g1, TPB, 0, stream>>>(pred, tgt, msk, part_d2, part_ms, bper);

    bcl_window_reduce<<<WBLKS, TPB, 0, stream>>>(part_d2, part_ms, blk_out, nchunks);

    bcl_final<<<1, 64, 0, stream>>>(blk_out, out, WBLKS);
}

// Round 2
// 167.868 us; speedup vs baseline: 1.0051x; 1.0051x over previous
//
#include <hip/hip_runtime.h>
#include <math.h>

// Problem constants (from reference setup_inputs)
#define BATCH 512
#define LEN   16384
#define WIN   5
#define WOUT  (LEN - WIN + 1)   // 16380
#define TPB   256
#define TILE  256
#define ELEMS (TILE + WIN - 1)  // 260

// Kernel 1: block = (window tile, batch chunk). For each batch row in the
// chunk, stage per-element quantities (m, t*m, p*m, p^2*m) through LDS once
// (sigmoid computed ONCE per element per block), then each thread computes
// its window's 5-tap sums from LDS. Accumulate sum_b d^2 and sum_b msum.
__global__ void bcl_partial_kernel(const float* __restrict__ pred,
                                   const int*   __restrict__ tgt,
                                   const int*   __restrict__ msk,
                                   float* __restrict__ part_d2,
                                   float* __restrict__ part_ms,
                                   int bper) {
    __shared__ float s_m[ELEMS], s_tm[ELEMS], s_pm[ELEMS], s_p2m[ELEMS];

    const int tile0 = blockIdx.x * TILE;
    const int j     = tile0 + threadIdx.x;   // window this thread owns
    const int b0    = blockIdx.y * bper;

    float accd2 = 0.f, accms = 0.f;

    for (int b = b0; b < b0 + bper; ++b) {
        __syncthreads();  // protect previous iteration's LDS reads
        // ---- stage 260 elements (1 sigmoid per element) ----
        for (int i = threadIdx.x; i < ELEMS; i += TPB) {
            const int e = tile0 + i;
            float m = 0.f, tmf = 0.f, p = 0.f;
            if (e < LEN) {
                const size_t base = (size_t)b * LEN + e;
                const int    mi = msk[base];
                const int    ti = tgt[base];
                const float2 p2 = ((const float2*)pred)[base];
                p   = 1.0f / (1.0f + __expf(p2.x - p2.y));  // softmax[...,1], C=2
                m   = (float)mi;
                tmf = (float)(ti & mi);                      // t*m, both in {0,1}
            }
            s_m[i]   = m;
            s_tm[i]  = tmf;
            s_pm[i]  = p * m;
            s_p2m[i] = p * p * m;
        }
        __syncthreads();
        // ---- window sums + variance diff ----
        if (j < WOUT) {
            float msum = 0.f, stm = 0.f, spm = 0.f, sp2m = 0.f;
#pragma unroll
            for (int k = 0; k < WIN; ++k) {
                const int i = threadIdx.x + k;
                msum += s_m[i];
                stm  += s_tm[i];
                spm  += s_pm[i];
                sp2m += s_p2m[i];
            }
            // st2m == stm since t in {0,1}
            const float denom = fmaxf(msum, 1.0f);
            const float inv   = 1.0f / denom;
            const float pmean = spm * inv;
            const float tmean = stm * inv;
            const float pvar  = (sp2m - 2.0f * pmean * spm + pmean * pmean * msum) * inv;
            const float tvar  = (stm  - 2.0f * tmean * stm + tmean * tmean * msum) * inv;
            const float d = pvar - tvar;
            accd2 += d * d;
            accms += msum;
        }
    }
    if (j < WOUT) {
        part_d2[(size_t)blockIdx.y * WOUT + j] = accd2;
        part_ms[(size_t)blockIdx.y * WOUT + j] = accms;
    }
}

// Kernel 2: per-window reduce over chunks -> mse*valid; block-reduce to
// doubles; atomicAdd into global accumulators; last block finalizes output.
__global__ void bcl_window_reduce(const float* __restrict__ part_d2,
                                  const float* __restrict__ part_ms,
                                  double* __restrict__ accum,  // [num, cnt]
                                  unsigned int* __restrict__ ticket,
                                  float* __restrict__ out,
                                  int nchunks) {
    const int j = blockIdx.x * blockDim.x + threadIdx.x;
    double num = 0.0, cnt = 0.0;
    if (j < WOUT) {
        float d2 = 0.f, ms = 0.f;
        for (int c = 0; c < nchunks; ++c) {
            d2 += part_d2[(size_t)c * WOUT + j];
            ms += part_ms[(size_t)c * WOUT + j];
        }
        if (ms > 0.f) {
            num = (double)d2 * (1.0 / (double)BATCH);
            cnt = 1.0;
        }
    }
    // wave reduce (wave = 64)
    for (int off = 32; off > 0; off >>= 1) {
        num += __shfl_down(num, off, 64);
        cnt += __shfl_down(cnt, off, 64);
    }
    __shared__ double s_num[4], s_cnt[4];
    const int lane = threadIdx.x & 63, wave = threadIdx.x >> 6;
    if (lane == 0) { s_num[wave] = num; s_cnt[wave] = cnt; }
    __syncthreads();
    if (threadIdx.x == 0) {
        double n = 0.0, c = 0.0;
        const int nw = (int)(blockDim.x >> 6);
        for (int wv = 0; wv < nw; ++wv) { n += s_num[wv]; c += s_cnt[wv]; }
        atomicAdd(&accum[0], n);
        atomicAdd(&accum[1], c);
        __threadfence();
        const unsigned int t = atomicAdd(ticket, 1u);
        if (t == gridDim.x - 1) {
            out[0] = (float)(accum[0] / fmax(accum[1], 1.0));
        }
    }
}

extern "C" void kernel_launch(void* const* d_in, const int* in_sizes, int n_in,
                              void* d_out, int out_size, void* d_ws, size_t ws_size,
                              hipStream_t stream) {
    const float* pred = (const float*)d_in[0];
    const int*   tgt  = (const int*)d_in[1];
    const int*   msk  = (const int*)d_in[2];
    float* out = (float*)d_out;

    // Pick largest batch-chunk count that fits in workspace (divides 512).
    int nchunks = 32;
    while (nchunks > 1) {
        size_t need = (size_t)nchunks * WOUT * 2 * sizeof(float) + 64;
        if (need <= ws_size) break;
        nchunks >>= 1;
    }
    const int bper = BATCH / nchunks;

    float* part_d2 = (float*)d_ws;
    float* part_ms = part_d2 + (size_t)nchunks * WOUT;
    // 8-byte-aligned tail region: [double num, double cnt, uint ticket]
    size_t off = ((size_t)nchunks * WOUT * 2 * sizeof(float) + 15) & ~(size_t)15;
    double* accum = (double*)((char*)d_ws + off);
    unsigned int* ticket = (unsigned int*)(accum + 2);

    // zero the accumulators + ticket (ws is re-poisoned to 0xAA every call)
    hipMemsetAsync((void*)accum, 0, 2 * sizeof(double) + sizeof(unsigned int), stream);

    const int WBLKS = (WOUT + TILE - 1) / TILE;  // 64

    dim3 g1(WBLKS, nchunks);
    bcl_partial_kernel<<<g1, TPB, 0, stream>>>(pred, tgt, msk, part_d2, part_ms, bper);

    bcl_window_reduce<<<WBLKS, TPB, 0, stream>>>(part_d2, part_ms, accum, ticket, out, nchunks);
}